// Round 9
// baseline (459.067 us; speedup 1.0000x reference)
//
#include <hip/hip_runtime.h>
#include <math.h>
#include <stdint.h>

#define N0   3000
#define NE   96000
#define INC  512
#define HIDF 256
#define OUTC 64
#define KP1  2000
#define KP2  1000
#define KP3  500
#define KP1P 2048
#define KP2P 1024
#define KP3P 512

typedef __bf16 bf16x8 __attribute__((ext_vector_type(8)));
typedef float f32x4 __attribute__((ext_vector_type(4)));

// global_load_lds: per-lane global src, wave-uniform LDS base (HW adds lane*16)
#define GLDS16(gp, lp)                                                   \
  __builtin_amdgcn_global_load_lds(                                      \
      (__attribute__((address_space(1))) void*)(gp),                     \
      (__attribute__((address_space(3))) void*)(lp), 16, 0, 0)

// ---------------- CSR build (in-edges by dst) ----------------
static __global__ void count_k(const int* __restrict__ ei, int* __restrict__ cd) {
  int e = blockIdx.x * blockDim.x + threadIdx.x;
  if (e < NE) atomicAdd(&cd[ei[NE + e]], 1);
}

static __global__ __launch_bounds__(1024) void scan_excl_k(const int* __restrict__ cnt,
                                                           int* __restrict__ start, int n,
                                                           float* __restrict__ dis0) {
  __shared__ int s[4096];
  int tid = threadIdx.x;
  for (int i = tid; i < 4096; i += blockDim.x) s[i] = (i < n) ? cnt[i] : 0;
  __syncthreads();
  for (int d = 1; d < 4096; d <<= 1) {
    int v[4]; int r = 0;
    for (int i = tid; i < 4096; i += blockDim.x, ++r) v[r] = (i >= d) ? s[i - d] : 0;
    __syncthreads();
    r = 0;
    for (int i = tid; i < 4096; i += blockDim.x, ++r) s[i] += v[r];
    __syncthreads();
  }
  for (int i = tid; i < n; i += blockDim.x) {
    start[i] = (i == 0) ? 0 : s[i - 1];
    dis0[i] = rsqrtf((float)cnt[i] + 2.0f);
  }
  if (tid == 0) start[n] = s[n - 1];
}

static __global__ void scatter_k(const int* __restrict__ ei, const int* __restrict__ sd,
                                 int* __restrict__ fd, int* __restrict__ bd) {
  int e = blockIdx.x * blockDim.x + threadIdx.x;
  if (e < NE) {
    int d = ei[NE + e];
    bd[sd[d] + atomicAdd(&fd[d], 1)] = ei[e];
  }
}

// ---------------- masked augment level 0 (bf16 out; counts exact) ----------------
static __global__ __launch_bounds__(256) void augA_masked_k(
    const int* __restrict__ st, const int* __restrict__ bk,
    const int* __restrict__ perm, const int* __restrict__ pos,
    __bf16* __restrict__ A1bf, float* __restrict__ dis1) {
  __shared__ float row[KP1];
  __shared__ float sh[4];
  int tid = threadIdx.x, lane = tid & 63, wave = tid >> 6;
  int r = blockIdx.x;
  int vi = perm[r];
  for (int c = tid; c < KP1; c += 256) row[c] = 0.f;
  __syncthreads();
  int b = st[vi], e = st[vi + 1];
  for (int t = b + wave; t < e; t += 4) {
    int k = bk[t];
    int jb = st[k], je = st[k + 1];
    for (int u = jb + lane; u < je; u += 64) {
      int p = pos[bk[u]];
      if (p >= 0) atomicAdd(&row[p], 1.0f);
    }
  }
  if (wave == 0)
    for (int t = b + lane; t < e; t += 64) {
      int p = pos[bk[t]];
      if (p >= 0) atomicAdd(&row[p], 2.0f);
    }
  __syncthreads();
  if (tid == 0) row[r] = 0.f;
  __syncthreads();
  float s = 0.f;
  for (int c = tid; c < KP1P; c += 256) {
    float v = (c < KP1) ? row[c] : 0.f;
    A1bf[(size_t)r * KP1P + c] = (__bf16)v;
    s += v;
  }
#pragma unroll
  for (int o = 32; o > 0; o >>= 1) s += __shfl_down(s, o, 64);
  if (lane == 0) sh[wave] = s;
  __syncthreads();
  if (tid == 0) dis1[r] = rsqrtf(sh[0] + sh[1] + sh[2] + sh[3] + 2.0f);
}

// ---------------- SpMM with fused source scaling ----------------
static __global__ void spmm_sc_k(const int* __restrict__ start, const int* __restrict__ idx,
                                 const float* __restrict__ xw, const float* __restrict__ dis,
                                 float* __restrict__ out, int F) {
  int row = blockIdx.x;
  int b = start[row], e = start[row + 1];
  int f = threadIdx.x;  // blockDim == F
  __shared__ int nb[256];
  __shared__ float nd[256];
  float acc = 0.f;
  for (int t0 = b; t0 < e; t0 += blockDim.x) {
    int m = min((int)blockDim.x, e - t0);
    __syncthreads();
    if (f < m) { int s = idx[t0 + f]; nb[f] = s; nd[f] = dis[s]; }
    __syncthreads();
    for (int t = 0; t < m; ++t) acc += xw[(size_t)nb[t] * F + f] * nd[t];
  }
  out[(size_t)row * F + f] = acc;
}

// ---------------- converters ----------------
static __global__ void conv_hilo_k(const float* __restrict__ in, int R, int C, int Cp,
                                   __bf16* __restrict__ oh, __bf16* __restrict__ ol) {
  int idx = blockIdx.x * blockDim.x + threadIdx.x;
  if (idx < R * Cp) {
    int r = idx / Cp, c = idx - r * Cp;
    float v = (c < C) ? in[(size_t)r * C + c] : 0.f;
    __bf16 h = (__bf16)v;
    oh[idx] = h;
    if (ol) ol[idx] = (__bf16)(v - (float)h);
  }
}

// batched weight transpose+hilo: 7 descriptors, grid.z selects
struct TDesc { const float* in; __bf16* oh; __bf16* ol; int R, C, Rp; };
struct TDescs { TDesc d[7]; };
static __global__ __launch_bounds__(256) void wtconv_k(TDescs ds) {
  TDesc d = ds.d[blockIdx.z];
  int r0 = blockIdx.x * 32, c0 = blockIdx.y * 32;
  if (r0 >= d.Rp || c0 >= d.C) return;
  __shared__ float t[32][33];
  int lr = threadIdx.x >> 5, lc = threadIdx.x & 31;
#pragma unroll
  for (int i = 0; i < 4; ++i) {
    int r = r0 + lr + i * 8, c = c0 + lc;
    t[lr + i * 8][lc] = (r < d.R && c < d.C) ? d.in[(size_t)r * d.C + c] : 0.f;
  }
  __syncthreads();
#pragma unroll
  for (int i = 0; i < 4; ++i) {
    int c = c0 + lr + i * 8, r = r0 + lc;
    if (c < d.C) {
      float v = t[lc][lr + i * 8];
      __bf16 h = (__bf16)v;
      d.oh[(size_t)c * d.Rp + r] = h;
      d.ol[(size_t)c * d.Rp + r] = (__bf16)(v - (float)h);
    }
  }
}

// bf16 transpose (optional lo pair)
static __global__ __launch_bounds__(256) void btrans_k(const __bf16* __restrict__ ih,
                                                       const __bf16* __restrict__ il,
                                                       __bf16* __restrict__ oh, __bf16* __restrict__ ol,
                                                       int Rin, int Ls, int Cout, int Lo) {
  __shared__ __bf16 th[32][40], tl[32][40];
  int r0 = blockIdx.x * 32, c0 = blockIdx.y * 32;
  int lr = threadIdx.x >> 5, lc = threadIdx.x & 31;
#pragma unroll
  for (int i = 0; i < 4; ++i) {
    int r = r0 + lr + i * 8, c = c0 + lc;
    bool ok = (r < Rin);
    th[lr + i * 8][lc] = ok ? ih[(size_t)r * Ls + c] : (__bf16)0.f;
    if (il) tl[lr + i * 8][lc] = ok ? il[(size_t)r * Ls + c] : (__bf16)0.f;
  }
  __syncthreads();
#pragma unroll
  for (int i = 0; i < 4; ++i) {
    int c = c0 + lr + i * 8, r = r0 + lc;
    if (c < Cout) {
      oh[(size_t)c * Lo + r] = th[lc][lr + i * 8];
      if (ol) ol[(size_t)c * Lo + r] = tl[lc][lr + i * 8];
    }
  }
}

// fused: reduce partials (ks=1 -> plain read) -> optional xw f32, transposed dis-scaled hi/lo
static __global__ __launch_bounds__(256) void redtconv_k(const float* __restrict__ Cp, int ks, int mn,
                                                         int R, int C, int Rp,
                                                         __bf16* __restrict__ oh, __bf16* __restrict__ ol,
                                                         const float* __restrict__ disv,
                                                         float* __restrict__ xw_out) {
  __shared__ float t[32][33];
  int r0 = blockIdx.x * 32, c0 = blockIdx.y * 32;
  int lr = threadIdx.x >> 5, lc = threadIdx.x & 31;
#pragma unroll
  for (int i = 0; i < 4; ++i) {
    int r = r0 + lr + i * 8, c = c0 + lc;
    float v = 0.f;
    if (r < R && c < C) {
      size_t idx = (size_t)r * C + c;
      for (int z = 0; z < ks; ++z) v += Cp[(size_t)z * mn + idx];
      if (xw_out) xw_out[idx] = v;
    }
    t[lr + i * 8][lc] = v;
  }
  __syncthreads();
#pragma unroll
  for (int i = 0; i < 4; ++i) {
    int c = c0 + lr + i * 8, r = r0 + lc;
    if (c < C) {
      float v = t[lc][lr + i * 8];
      if (r < R) v *= disv[r];
      __bf16 h = (__bf16)v;
      oh[(size_t)c * Rp + r] = h;
      ol[(size_t)c * Rp + r] = (__bf16)(v - (float)h);
    }
  }
}

static __global__ void ghilo_k(const float* __restrict__ src, const int* __restrict__ perm,
                               const float* __restrict__ sv, __bf16* __restrict__ oh,
                               __bf16* __restrict__ ol, int k) {
  int idx = blockIdx.x * blockDim.x + threadIdx.x;
  if (idx < k * HIDF) {
    int r = idx >> 8;
    float v = src[(size_t)perm[r] * HIDF + (idx & 255)] * sv[r];
    __bf16 h = (__bf16)v;
    oh[idx] = h;
    ol[idx] = (__bf16)(v - (float)h);
  }
}

// ---------------- MFMA GEMM: split-K, global_load_lds, dbuf, optional row-gather ----------------
template <int BM, int BN>
static __global__ __launch_bounds__(256) void mgemm_k(
    const __bf16* __restrict__ A0, const __bf16* __restrict__ A1g, const __bf16* __restrict__ A2g,
    const __bf16* __restrict__ B0, const __bf16* __restrict__ B1g, const __bf16* __restrict__ B2g,
    const int* __restrict__ pA, const int* __restrict__ pB,
    int nseg, float* __restrict__ Cp, int M, int N, int Kp, int kchunk) {
  constexpr int FM = BM / 32, FN = BN / 32;
  __shared__ __bf16 As[2][BM * 64];
  __shared__ __bf16 Bs[2][BN * 64];
  int tid = threadIdx.x;
  int lane = tid & 63, wave = tid >> 6;
  int wx = wave & 1, wy = wave >> 1;
  int l15 = lane & 15, l4 = lane >> 4;
  int brow = blockIdx.y * BM, bcol = blockIdx.x * BN;
  int wrow = wy * (BM / 2), wcol = wx * (BN / 2);
  int srow = lane >> 3, slot = lane & 7;
  int k_beg = blockIdx.z * kchunk;
  int ksteps = kchunk >> 6;
  int nsteps = nseg * ksteps;
  const __bf16* segA[3] = {A0, A1g, A2g};
  const __bf16* segB[3] = {B0, B1g, B2g};

  // hoisted row indices (gather resolved once, not per K-step)
  int rowA[BM / 32], rowB[BN / 32];
#pragma unroll
  for (int i = 0; i < BM / 32; ++i) {
    int rl = (i * 4 + wave) * 8 + srow;
    int gr = brow + rl;
    if (gr >= M) gr = M - 1;
    rowA[i] = pA ? pA[gr] : gr;
  }
#pragma unroll
  for (int i = 0; i < BN / 32; ++i) {
    int rl = (i * 4 + wave) * 8 + srow;
    int gc = bcol + rl;
    if (gc >= N) gc = N - 1;
    rowB[i] = pB ? pB[gc] : gc;
  }

  auto stage = [&](int buf, int t) {
    int seg = t / ksteps;
    int k0 = k_beg + ((t - seg * ksteps) << 6);
    const __bf16* Ag = segA[seg];
    const __bf16* Bg = segB[seg];
#pragma unroll
    for (int i = 0; i < BM / 32; ++i) {
      int rl = (i * 4 + wave) * 8 + srow;
      int col = k0 + ((slot ^ (rl & 7)) << 3);
      GLDS16(Ag + (size_t)rowA[i] * Kp + col, &As[buf][(i * 4 + wave) * 8 * 64]);
    }
#pragma unroll
    for (int i = 0; i < BN / 32; ++i) {
      int rl = (i * 4 + wave) * 8 + srow;
      int col = k0 + ((slot ^ (rl & 7)) << 3);
      GLDS16(Bg + (size_t)rowB[i] * Kp + col, &Bs[buf][(i * 4 + wave) * 8 * 64]);
    }
  };

  f32x4 acc[FM][FN] = {};
  stage(0, 0);
  __syncthreads();
  int cur = 0;
  for (int t = 0; t < nsteps; ++t) {
    if (t + 1 < nsteps) stage(cur ^ 1, t + 1);
#pragma unroll
    for (int sub = 0; sub < 2; ++sub) {
      bf16x8 af[FM], bfv[FN];
#pragma unroll
      for (int i = 0; i < FM; ++i) {
        int r = wrow + i * 16 + l15;
        af[i] = *(const bf16x8*)(&As[cur][r * 64 + (((sub * 4 + l4) ^ (r & 7)) << 3)]);
      }
#pragma unroll
      for (int j = 0; j < FN; ++j) {
        int r = wcol + j * 16 + l15;
        bfv[j] = *(const bf16x8*)(&Bs[cur][r * 64 + (((sub * 4 + l4) ^ (r & 7)) << 3)]);
      }
#pragma unroll
      for (int i = 0; i < FM; ++i)
#pragma unroll
        for (int j = 0; j < FN; ++j)
          acc[i][j] = __builtin_amdgcn_mfma_f32_16x16x32_bf16(af[i], bfv[j], acc[i][j], 0, 0, 0);
    }
    __syncthreads();
    cur ^= 1;
  }
  size_t zoff = (size_t)blockIdx.z * M * N;
#pragma unroll
  for (int i = 0; i < FM; ++i)
#pragma unroll
    for (int j = 0; j < FN; ++j) {
      int col = bcol + wcol + j * 16 + l15;
      if (col < N) {
#pragma unroll
        for (int q = 0; q < 4; ++q) {
          int row = brow + wrow + i * 16 + l4 * 4 + q;
          if (row < M) Cp[zoff + (size_t)row * N + col] = acc[i][j][q];
        }
      }
    }
}

// ---------------- epilogues ----------------
// conv epilogue fused with pooling score (f == HIDF, one block per row)
static __global__ __launch_bounds__(256) void epi_score_k(
    const float* __restrict__ zp, int ks, int mn, const float* __restrict__ xw,
    const float* __restrict__ disv, const float* __restrict__ bias,
    const float* __restrict__ p, float* __restrict__ outx, float* __restrict__ sc) {
  int r = blockIdx.x, tid = threadIdx.x;
  size_t idx = (size_t)r * HIDF + tid;
  float zv = 0.f;
  for (int z = 0; z < ks; ++z) zv += zp[(size_t)z * mn + idx];
  float di = disv[r];
  float v = di * zv + 2.0f * di * di * xw[idx] + bias[tid];
  v = fmaxf(v, 0.0f);
  outx[idx] = v;
  float wv = p[tid];
  float s = v * wv, q = wv * wv;
  __shared__ float sh[4], sh2[4];
  int lane = tid & 63, wid = tid >> 6;
#pragma unroll
  for (int o = 32; o > 0; o >>= 1) { s += __shfl_down(s, o, 64); q += __shfl_down(q, o, 64); }
  if (lane == 0) { sh[wid] = s; sh2[wid] = q; }
  __syncthreads();
  if (tid == 0)
    sc[r] = tanhf((sh[0] + sh[1] + sh[2] + sh[3]) / sqrtf(sh2[0] + sh2[1] + sh2[2] + sh2[3]));
}

// conv epilogue fused into unpool consumer
static __global__ void unpool_epi_k(const float* __restrict__ base, const float* __restrict__ zp,
                                    int ks, int mn, const float* __restrict__ xwp,
                                    const float* __restrict__ disv, const float* __restrict__ bias,
                                    const int* __restrict__ pos, __bf16* __restrict__ oh,
                                    __bf16* __restrict__ ol, int n) {
  int idx = blockIdx.x * blockDim.x + threadIdx.x;
  if (idx < n * HIDF) {
    int i = idx >> 8, j = idx & 255;
    int p = pos[i];
    float v = base[idx];
    if (p >= 0) {
      size_t pidx = (size_t)p * HIDF + j;
      float zv = 0.f;
      for (int z = 0; z < ks; ++z) zv += zp[(size_t)z * mn + pidx];
      float di = disv[p];
      float u = di * zv + 2.0f * di * di * xwp[pidx] + bias[j];
      v += fmaxf(u, 0.0f);
    }
    __bf16 h = (__bf16)v;
    oh[idx] = h;
    ol[idx] = (__bf16)(v - (float)h);
  }
}

// split-K reduce + (+2*A[perm[r]][perm[c]]) + zero diag + rowsum->dis + hi/lo out
static __global__ __launch_bounds__(256) void aug_epi_k(
    const float* __restrict__ Cp, int ks, int mn, int n, int dstL,
    const __bf16* __restrict__ srcH, const __bf16* __restrict__ srcL, int srcLen,
    const int* __restrict__ permv, __bf16* __restrict__ bh, __bf16* __restrict__ bl,
    float* __restrict__ dis) {
  __shared__ int pm[1000];
  __shared__ float srow[2048];
  __shared__ float sh[4];
  int r = blockIdx.x;
  int tid = threadIdx.x, lane = tid & 63, wave = tid >> 6;
  int vi = permv[r];
  for (int c = tid; c < n; c += 256) pm[c] = permv[c];
  for (int k = tid; k < srcLen; k += 256) {
    float v = (float)srcH[(size_t)vi * srcLen + k];
    if (srcL) v += (float)srcL[(size_t)vi * srcLen + k];
    srow[k] = v;
  }
  __syncthreads();
  float ssum = 0.f;
  for (int c = tid; c < dstL; c += 256) {
    float v = 0.f;
    if (c < n && c != r) {
      for (int z = 0; z < ks; ++z) v += Cp[(size_t)z * mn + (size_t)r * n + c];
      v += 2.0f * srow[pm[c]];
    }
    __bf16 h = (__bf16)v;
    bh[(size_t)r * dstL + c] = h;
    bl[(size_t)r * dstL + c] = (__bf16)(v - (float)h);
    ssum += v;
  }
#pragma unroll
  for (int o = 32; o > 0; o >>= 1) ssum += __shfl_down(ssum, o, 64);
  if (lane == 0) sh[wave] = ssum;
  __syncthreads();
  if (tid == 0) dis[r] = rsqrtf(sh[0] + sh[1] + sh[2] + sh[3] + 2.0f);
}

// ---------------- pooling ----------------
static __global__ __launch_bounds__(256) void topk_rank_k(const float* __restrict__ sc, int n, int k,
                                                          int* __restrict__ perm, float* __restrict__ sv,
                                                          int* __restrict__ pos) {
  __shared__ float s[N0 + 8];
  int tid = threadIdx.x, lane = tid & 63, wave = tid >> 6;
  for (int i = tid; i < n; i += 256) s[i] = sc[i];
  __syncthreads();
  int i = blockIdx.x * 4 + wave;
  if (i < n) {
    float si = s[i];
    int rank = 0;
    for (int j = lane; j < n; j += 64) {
      float sj = s[j];
      rank += (sj > si) || (sj == si && j < i);
    }
#pragma unroll
    for (int o = 32; o > 0; o >>= 1) rank += __shfl_down(rank, o, 64);
    if (lane == 0) {
      pos[i] = (rank < k) ? rank : -1;
      if (rank < k) { perm[rank] = i; sv[rank] = si; }
    }
  }
}

// fused final epilogue + log_softmax
static __global__ void epilsm_k(const float* __restrict__ zb, const float* __restrict__ xw,
                                const float* __restrict__ dis, const float* __restrict__ b,
                                float* __restrict__ out) {
  int r = blockIdx.x, j = threadIdx.x;
  float di = dis[r];
  float v = di * zb[r * OUTC + j] + 2.0f * di * di * xw[r * OUTC + j] + b[j];
  float m = v;
#pragma unroll
  for (int o = 32; o > 0; o >>= 1) m = fmaxf(m, __shfl_xor(m, o, 64));
  float e = expf(v - m), s = e;
#pragma unroll
  for (int o = 32; o > 0; o >>= 1) s += __shfl_xor(s, o, 64);
  out[r * OUTC + j] = v - m - logf(s);
}

// ---------------- host ----------------
extern "C" void kernel_launch(void* const* d_in, const int* in_sizes, int n_in,
                              void* d_out, int out_size, void* d_ws, size_t ws_size,
                              hipStream_t stream) {
  const float* x  = (const float*)d_in[0];
  const int* ei   = (const int*)d_in[1];
  const float* W0 = (const float*)d_in[2];
  const float* b0 = (const float*)d_in[3];
  const float* W1 = (const float*)d_in[4];
  const float* b1 = (const float*)d_in[5];
  const float* W2 = (const float*)d_in[6];
  const float* b2 = (const float*)d_in[7];
  const float* W3 = (const float*)d_in[8];
  const float* b3 = (const float*)d_in[9];
  const float* p1 = (const float*)d_in[10];
  const float* p2 = (const float*)d_in[11];
  const float* p3 = (const float*)d_in[12];
  const float* U0 = (const float*)d_in[13];
  const float* c0 = (const float*)d_in[14];
  const float* U1 = (const float*)d_in[15];
  const float* c1 = (const float*)d_in[16];
  const float* U2 = (const float*)d_in[17];
  const float* c2 = (const float*)d_in[18];
  (void)in_sizes; (void)n_in; (void)out_size; (void)ws_size;

  char* basep = (char*)d_ws;
  size_t off = 0;
  auto alloc = [&](size_t bytes) {
    void* p = basep + off;
    off += (bytes + 255) & ~(size_t)255;
    return p;
  };

  // fp32
  float* xw  = (float*)alloc((size_t)N0 * HIDF * 4);
  float* zb  = (float*)alloc((size_t)N0 * HIDF * 4);
  float* x0  = (float*)alloc((size_t)N0 * HIDF * 4);
  float* x1  = (float*)alloc((size_t)KP1 * HIDF * 4);
  float* x2  = (float*)alloc((size_t)KP2 * HIDF * 4);
  float* Cpart = (float*)alloc((size_t)20 * 1024 * 1024);
  // bf16
  __bf16* bfAh = (__bf16*)alloc((size_t)N0 * INC * 2);
  __bf16* bfAl = (__bf16*)alloc((size_t)N0 * INC * 2);
  __bf16* bfBh = (__bf16*)alloc((size_t)HIDF * KP1P * 2);
  __bf16* bfBl = (__bf16*)alloc((size_t)HIDF * KP1P * 2);
  __bf16* A1bf  = (__bf16*)alloc((size_t)KP1 * KP1P * 2);
  __bf16* A1tbf = (__bf16*)alloc((size_t)KP1 * KP1P * 2);
  __bf16* A2bh  = (__bf16*)alloc((size_t)KP2 * KP2P * 2);
  __bf16* A2bl  = (__bf16*)alloc((size_t)KP2 * KP2P * 2);
  __bf16* A2tbh = (__bf16*)alloc((size_t)KP2 * KP2P * 2);
  __bf16* A2tbl = (__bf16*)alloc((size_t)KP2 * KP2P * 2);
  __bf16* A3bh  = (__bf16*)alloc((size_t)KP3 * KP3P * 2);
  __bf16* A3bl  = (__bf16*)alloc((size_t)KP3 * KP3P * 2);
  // weight operands
  __bf16* w0h = (__bf16*)alloc((size_t)HIDF * 512 * 2);
  __bf16* w0l = (__bf16*)alloc((size_t)HIDF * 512 * 2);
  __bf16* w1h = (__bf16*)alloc((size_t)HIDF * 256 * 2);
  __bf16* w1l = (__bf16*)alloc((size_t)HIDF * 256 * 2);
  __bf16* w2h = (__bf16*)alloc((size_t)HIDF * 256 * 2);
  __bf16* w2l = (__bf16*)alloc((size_t)HIDF * 256 * 2);
  __bf16* w3h = (__bf16*)alloc((size_t)HIDF * 256 * 2);
  __bf16* w3l = (__bf16*)alloc((size_t)HIDF * 256 * 2);
  __bf16* u0h = (__bf16*)alloc((size_t)HIDF * 256 * 2);
  __bf16* u0l = (__bf16*)alloc((size_t)HIDF * 256 * 2);
  __bf16* u1h = (__bf16*)alloc((size_t)HIDF * 256 * 2);
  __bf16* u1l = (__bf16*)alloc((size_t)HIDF * 256 * 2);
  __bf16* u2h = (__bf16*)alloc((size_t)OUTC * 256 * 2);
  __bf16* u2l = (__bf16*)alloc((size_t)OUTC * 256 * 2);
  // small
  float* sc   = (float*)alloc(N0 * 4);
  float* sv   = (float*)alloc(KP1 * 4);
  int* perm1  = (int*)alloc(KP1 * 4);
  int* perm2  = (int*)alloc(KP2 * 4);
  int* perm3  = (int*)alloc(KP3 * 4);
  int* pos1   = (int*)alloc(N0 * 4);
  int* pos2   = (int*)alloc(KP1 * 4);
  int* pos3   = (int*)alloc(KP2 * 4);
  float* dis0 = (float*)alloc(N0 * 4);
  float* dis1 = (float*)alloc(KP1 * 4);
  float* dis2 = (float*)alloc(KP2 * 4);
  float* dis3 = (float*)alloc(KP3 * 4);
  int* cf     = (int*)alloc((size_t)2 * 3072 * 4);
  int* cnt_d  = cf;
  int* fl_d   = cf + 3072;
  int* st_d   = (int*)alloc((N0 + 4) * 4);
  int* bk_d   = (int*)alloc(NE * 4);

  auto mg = [&](int bm, int bn, const __bf16* a0, const __bf16* a1, const __bf16* a2,
                const __bf16* bb0, const __bf16* bb1, const __bf16* bb2,
                const int* pA, const int* pB, int nseg, float* Cdst,
                int M, int N, int Kp, int ks, int kchunk) {
    dim3 g((N + bn - 1) / bn, (M + bm - 1) / bm, ks);
    if (bm == 128 && bn == 128)
      mgemm_k<128, 128><<<g, 256, 0, stream>>>(a0, a1, a2, bb0, bb1, bb2, pA, pB, nseg, Cdst, M, N, Kp, kchunk);
    else if (bm == 128)
      mgemm_k<128, 64><<<g, 256, 0, stream>>>(a0, a1, a2, bb0, bb1, bb2, pA, pB, nseg, Cdst, M, N, Kp, kchunk);
    else
      mgemm_k<64, 64><<<g, 256, 0, stream>>>(a0, a1, a2, bb0, bb1, bb2, pA, pB, nseg, Cdst, M, N, Kp, kchunk);
  };

  // weight GEMM: ks=1, direct write to xw (no partials, no reduce)
  auto wgemm = [&](const __bf16* wh, const __bf16* wl, int fin, int fout, int n) {
    int Kp = (fin + 63) & ~63;
    mg(64, 64, bfAh, bfAh, bfAl, wh, wl, wh, nullptr, nullptr, 3, xw, n, fout, Kp, 1, Kp);
  };

  // prop GEMM: B-operand from xw (ks=1 read), GEMM into Cpart with split-K
  auto propg = [&](const __bf16* Abh, const __bf16* Abl, int asegs, int n, int Kp, int bm,
                   int ks, int kchunk, const float* disv) {
    dim3 tg(Kp / 32, HIDF / 32);
    redtconv_k<<<tg, 256, 0, stream>>>(xw, 1, 0, n, HIDF, Kp, bfBh, bfBl, disv, nullptr);
    if (asegs == 1) mg(bm, 64, Abh, Abh, nullptr, bfBh, bfBl, nullptr, nullptr, nullptr, 2, Cpart, n, HIDF, Kp, ks, kchunk);
    else            mg(bm, 64, Abh, Abh, Abl, bfBh, bfBl, bfBh, nullptr, nullptr, 3, Cpart, n, HIDF, Kp, ks, kchunk);
  };

  // ---- CSR build + weight conversions ----
  hipMemsetAsync(cf, 0, (size_t)2 * 3072 * 4, stream);
  count_k<<<(NE + 255) / 256, 256, 0, stream>>>(ei, cnt_d);
  {
    TDescs ds;
    ds.d[0] = {W0, w0h, w0l, INC, HIDF, 512};
    ds.d[1] = {W1, w1h, w1l, HIDF, HIDF, 256};
    ds.d[2] = {W2, w2h, w2l, HIDF, HIDF, 256};
    ds.d[3] = {W3, w3h, w3l, HIDF, HIDF, 256};
    ds.d[4] = {U0, u0h, u0l, HIDF, HIDF, 256};
    ds.d[5] = {U1, u1h, u1l, HIDF, HIDF, 256};
    ds.d[6] = {U2, u2h, u2l, HIDF, OUTC, 256};
    wtconv_k<<<dim3(16, 8, 7), 256, 0, stream>>>(ds);
  }
  scan_excl_k<<<1, 1024, 0, stream>>>(cnt_d, st_d, N0, dis0);
  scatter_k<<<(NE + 255) / 256, 256, 0, stream>>>(ei, st_d, fl_d, bk_d);

  // ---- down conv 0 (sparse propagation), epi fused with score(p1) ----
  conv_hilo_k<<<((size_t)N0 * INC + 255) / 256, 256, 0, stream>>>(x, N0, INC, INC, bfAh, bfAl);
  wgemm(w0h, w0l, INC, HIDF, N0);
  spmm_sc_k<<<N0, HIDF, 0, stream>>>(st_d, bk_d, xw, dis0, zb, HIDF);
  epi_score_k<<<N0, 256, 0, stream>>>(zb, 1, 0, xw, dis0, b0, p1, x0, sc);
  topk_rank_k<<<(N0 + 3) / 4, 256, 0, stream>>>(sc, N0, KP1, perm1, sv, pos1);

  // ---- masked augment(A) ----
  augA_masked_k<<<KP1, 256, 0, stream>>>(st_d, bk_d, perm1, pos1, A1bf, dis1);

  // ---- conv 1, epi fused with score(p2) ----
  ghilo_k<<<((size_t)KP1 * HIDF + 255) / 256, 256, 0, stream>>>(x0, perm1, sv, bfAh, bfAl, KP1);
  wgemm(w1h, w1l, HIDF, HIDF, KP1);
  propg(A1bf, nullptr, 1, KP1, KP1P, 128, 4, 512, dis1);
  epi_score_k<<<KP1, 256, 0, stream>>>(Cpart, 4, KP1 * HIDF, xw, dis1, b1, p2, x1, sc);
  topk_rank_k<<<(KP1 + 3) / 4, 256, 0, stream>>>(sc, KP1, KP2, perm2, sv, pos2);

  // ---- augment(A1): gathered GEMM + epi (+2A term in epi) ----
  btrans_k<<<dim3(KP1P / 32, (KP1 + 31) / 32), 256, 0, stream>>>(A1bf, nullptr, A1tbf, nullptr,
                                                                 KP1, KP1P, KP1, KP1P);
  mg(128, 128, A1bf, nullptr, nullptr, A1tbf, nullptr, nullptr, perm2, perm2,
     1, Cpart, KP2, KP2, KP1P, 2, 1024);
  aug_epi_k<<<KP2, 256, 0, stream>>>(Cpart, 2, KP2 * KP2, KP2, KP2P, A1bf, nullptr, KP1P, perm2,
                                     A2bh, A2bl, dis2);

  // ---- conv 2, epi fused with score(p3) ----
  ghilo_k<<<((size_t)KP2 * HIDF + 255) / 256, 256, 0, stream>>>(x1, perm2, sv, bfAh, bfAl, KP2);
  wgemm(w2h, w2l, HIDF, HIDF, KP2);
  propg(A2bh, A2bl, 2, KP2, KP2P, 128, 4, 256, dis2);
  epi_score_k<<<KP2, 256, 0, stream>>>(Cpart, 4, KP2 * HIDF, xw, dis2, b2, p3, x2, sc);
  topk_rank_k<<<(KP2 + 3) / 4, 256, 0, stream>>>(sc, KP2, KP3, perm3, sv, pos3);

  // ---- augment(A2): gathered GEMM hi/lo + epi ----
  btrans_k<<<dim3(KP2P / 32, (KP2 + 31) / 32), 256, 0, stream>>>(A2bh, A2bl, A2tbh, A2tbl,
                                                                 KP2, KP2P, KP2, KP2P);
  mg(64, 64, A2bh, A2bh, A2bl, A2tbh, A2tbl, A2tbh, perm3, perm3, 3, Cpart, KP3, KP3, KP2P, 2, 512);
  aug_epi_k<<<KP3, 256, 0, stream>>>(Cpart, 2, KP3 * KP3, KP3, KP3P, A2bh, A2bl, KP2P, perm3,
                                     A3bh, A3bl, dis3);

  // ---- conv 3 (epi fused into first unpool) ----
  ghilo_k<<<((size_t)KP3 * HIDF + 255) / 256, 256, 0, stream>>>(x2, perm3, sv, bfAh, bfAl, KP3);
  wgemm(w3h, w3l, HIDF, HIDF, KP3);
  propg(A3bh, A3bl, 2, KP3, KP3P, 64, 4, 128, dis3);
  unpool_epi_k<<<(KP2 * HIDF + 255) / 256, 256, 0, stream>>>(x2, Cpart, 4, KP3 * HIDF, xw, dis3, b3,
                                                             pos3, bfAh, bfAl, KP2);

  // ---- up conv on A2 (epi fused into next unpool) ----
  wgemm(u0h, u0l, HIDF, HIDF, KP2);
  propg(A2bh, A2bl, 2, KP2, KP2P, 128, 4, 256, dis2);
  unpool_epi_k<<<(KP1 * HIDF + 255) / 256, 256, 0, stream>>>(x1, Cpart, 4, KP2 * HIDF, xw, dis2, c0,
                                                             pos2, bfAh, bfAl, KP1);

  // ---- up conv on A1 (epi fused into next unpool) ----
  wgemm(u1h, u1l, HIDF, HIDF, KP1);
  propg(A1bf, nullptr, 1, KP1, KP1P, 128, 4, 512, dis1);
  unpool_epi_k<<<(N0 * HIDF + 255) / 256, 256, 0, stream>>>(x0, Cpart, 4, KP1 * HIDF, xw, dis1, c1,
                                                            pos1, bfAh, bfAl, N0);

  // ---- final conv on A (sparse) + log_softmax ----
  wgemm(u2h, u2l, HIDF, OUTC, N0);
  spmm_sc_k<<<N0, OUTC, 0, stream>>>(st_d, bk_d, xw, dis0, zb, OUTC);
  epilsm_k<<<N0, OUTC, 0, stream>>>(zb, xw, dis0, c2, (float*)d_out);
}

// Round 11
// 439.646 us; speedup vs baseline: 1.0442x; 1.0442x over previous
//
#include <hip/hip_runtime.h>
#include <math.h>
#include <stdint.h>

#define N0   3000
#define NE   96000
#define INC  512
#define HIDF 256
#define OUTC 64
#define KP1  2000
#define KP2  1000
#define KP3  500
#define KP1P 2048
#define KP2P 1024
#define KP3P 512

typedef __bf16 bf16x8 __attribute__((ext_vector_type(8)));
typedef float f32x4 __attribute__((ext_vector_type(4)));

// global_load_lds: per-lane global src, wave-uniform LDS base (HW adds lane*16)
#define GLDS16(gp, lp)                                                   \
  __builtin_amdgcn_global_load_lds(                                      \
      (__attribute__((address_space(1))) void*)(gp),                     \
      (__attribute__((address_space(3))) void*)(lp), 16, 0, 0)

// ---------------- CSR build (in-edges by dst) ----------------
static __global__ void count_k(const int* __restrict__ ei, int* __restrict__ cd) {
  int e = blockIdx.x * blockDim.x + threadIdx.x;
  if (e < NE) atomicAdd(&cd[ei[NE + e]], 1);
}

static __global__ __launch_bounds__(1024) void scan_excl_k(const int* __restrict__ cnt,
                                                           int* __restrict__ start, int n,
                                                           float* __restrict__ dis0) {
  __shared__ int s[4096];
  int tid = threadIdx.x;
  for (int i = tid; i < 4096; i += blockDim.x) s[i] = (i < n) ? cnt[i] : 0;
  __syncthreads();
  for (int d = 1; d < 4096; d <<= 1) {
    int v[4]; int r = 0;
    for (int i = tid; i < 4096; i += blockDim.x, ++r) v[r] = (i >= d) ? s[i - d] : 0;
    __syncthreads();
    r = 0;
    for (int i = tid; i < 4096; i += blockDim.x, ++r) s[i] += v[r];
    __syncthreads();
  }
  for (int i = tid; i < n; i += blockDim.x) {
    start[i] = (i == 0) ? 0 : s[i - 1];
    dis0[i] = rsqrtf((float)cnt[i] + 2.0f);
  }
  if (tid == 0) start[n] = s[n - 1];
}

static __global__ void scatter_k(const int* __restrict__ ei, const int* __restrict__ sd,
                                 int* __restrict__ fd, int* __restrict__ bd) {
  int e = blockIdx.x * blockDim.x + threadIdx.x;
  if (e < NE) {
    int d = ei[NE + e];
    bd[sd[d] + atomicAdd(&fd[d], 1)] = ei[e];
  }
}

// ---------------- masked augment level 0 ----------------
// emits Ahat1 = (A^2+2A)[perm,perm] offdiag + 2I  (diag=2 exact); dis1 = rsqrt(rowsum(Ahat1))
static __global__ __launch_bounds__(256) void augA_masked_k(
    const int* __restrict__ st, const int* __restrict__ bk,
    const int* __restrict__ perm, const int* __restrict__ pos,
    __bf16* __restrict__ A1bf, float* __restrict__ dis1) {
  __shared__ float row[KP1];
  __shared__ float sh[4];
  int tid = threadIdx.x, lane = tid & 63, wave = tid >> 6;
  int r = blockIdx.x;
  int vi = perm[r];
  for (int c = tid; c < KP1; c += 256) row[c] = 0.f;
  __syncthreads();
  int b = st[vi], e = st[vi + 1];
  for (int t = b + wave; t < e; t += 4) {
    int k = bk[t];
    int jb = st[k], je = st[k + 1];
    for (int u = jb + lane; u < je; u += 64) {
      int p = pos[bk[u]];
      if (p >= 0) atomicAdd(&row[p], 1.0f);
    }
  }
  if (wave == 0)
    for (int t = b + lane; t < e; t += 64) {
      int p = pos[bk[t]];
      if (p >= 0) atomicAdd(&row[p], 2.0f);
    }
  __syncthreads();
  if (tid == 0) row[r] = 2.0f;  // +2I folded into operand
  __syncthreads();
  float s = 0.f;
  for (int c = tid; c < KP1P; c += 256) {
    float v = (c < KP1) ? row[c] : 0.f;
    A1bf[(size_t)r * KP1P + c] = (__bf16)v;
    s += v;
  }
#pragma unroll
  for (int o = 32; o > 0; o >>= 1) s += __shfl_down(s, o, 64);
  if (lane == 0) sh[wave] = s;
  __syncthreads();
  if (tid == 0) dis1[r] = rsqrtf(sh[0] + sh[1] + sh[2] + sh[3]);  // rowsum already includes +2
}

// ---------------- SpMM + fused source scaling + fused 2*dis*xw self term ----------------
static __global__ void spmm_sc_k(const int* __restrict__ start, const int* __restrict__ idx,
                                 const float* __restrict__ xw, const float* __restrict__ dis,
                                 float* __restrict__ out, int F) {
  int row = blockIdx.x;
  int b = start[row], e = start[row + 1];
  int f = threadIdx.x;  // blockDim == F
  __shared__ int nb[256];
  __shared__ float nd[256];
  float acc = 2.0f * dis[row] * xw[(size_t)row * F + f];  // Ah=A+2I self term
  for (int t0 = b; t0 < e; t0 += blockDim.x) {
    int m = min((int)blockDim.x, e - t0);
    __syncthreads();
    if (f < m) { int s = idx[t0 + f]; nb[f] = s; nd[f] = dis[s]; }
    __syncthreads();
    for (int t = 0; t < m; ++t) acc += xw[(size_t)nb[t] * F + f] * nd[t];
  }
  out[(size_t)row * F + f] = acc;
}

// ---------------- converters ----------------
static __global__ void conv_hilo_k(const float* __restrict__ in, int R, int C, int Cp,
                                   __bf16* __restrict__ oh, __bf16* __restrict__ ol) {
  int idx = blockIdx.x * blockDim.x + threadIdx.x;
  if (idx < R * Cp) {
    int r = idx / Cp, c = idx - r * Cp;
    float v = (c < C) ? in[(size_t)r * C + c] : 0.f;
    __bf16 h = (__bf16)v;
    oh[idx] = h;
    if (ol) ol[idx] = (__bf16)(v - (float)h);
  }
}

// batched weight transpose+hilo: 7 descriptors, grid.z selects
struct TDesc { const float* in; __bf16* oh; __bf16* ol; int R, C, Rp; };
struct TDescs { TDesc d[7]; };
static __global__ __launch_bounds__(256) void wtconv_k(TDescs ds) {
  TDesc d = ds.d[blockIdx.z];
  int r0 = blockIdx.x * 32, c0 = blockIdx.y * 32;
  if (r0 >= d.Rp || c0 >= d.C) return;
  __shared__ float t[32][33];
  int lr = threadIdx.x >> 5, lc = threadIdx.x & 31;
#pragma unroll
  for (int i = 0; i < 4; ++i) {
    int r = r0 + lr + i * 8, c = c0 + lc;
    t[lr + i * 8][lc] = (r < d.R && c < d.C) ? d.in[(size_t)r * d.C + c] : 0.f;
  }
  __syncthreads();
#pragma unroll
  for (int i = 0; i < 4; ++i) {
    int c = c0 + lr + i * 8, r = r0 + lc;
    if (c < d.C) {
      float v = t[lc][lr + i * 8];
      __bf16 h = (__bf16)v;
      d.oh[(size_t)c * d.Rp + r] = h;
      d.ol[(size_t)c * d.Rp + r] = (__bf16)(v - (float)h);
    }
  }
}

// bf16 transpose (optional lo pair)
static __global__ __launch_bounds__(256) void btrans_k(const __bf16* __restrict__ ih,
                                                       const __bf16* __restrict__ il,
                                                       __bf16* __restrict__ oh, __bf16* __restrict__ ol,
                                                       int Rin, int Ls, int Cout, int Lo) {
  __shared__ __bf16 th[32][40], tl[32][40];
  int r0 = blockIdx.x * 32, c0 = blockIdx.y * 32;
  int lr = threadIdx.x >> 5, lc = threadIdx.x & 31;
#pragma unroll
  for (int i = 0; i < 4; ++i) {
    int r = r0 + lr + i * 8, c = c0 + lc;
    bool ok = (r < Rin);
    th[lr + i * 8][lc] = ok ? ih[(size_t)r * Ls + c] : (__bf16)0.f;
    if (il) tl[lr + i * 8][lc] = ok ? il[(size_t)r * Ls + c] : (__bf16)0.f;
  }
  __syncthreads();
#pragma unroll
  for (int i = 0; i < 4; ++i) {
    int c = c0 + lr + i * 8, r = r0 + lc;
    if (c < Cout) {
      oh[(size_t)c * Lo + r] = th[lc][lr + i * 8];
      if (ol) ol[(size_t)c * Lo + r] = tl[lc][lr + i * 8];
    }
  }
}

// reduce (ks=1: plain read) -> transposed dis-scaled hi/lo [C][Rp]
static __global__ __launch_bounds__(256) void redtconv_k(const float* __restrict__ Cp, int ks, int mn,
                                                         int R, int C, int Rp,
                                                         __bf16* __restrict__ oh, __bf16* __restrict__ ol,
                                                         const float* __restrict__ disv) {
  __shared__ float t[32][33];
  int r0 = blockIdx.x * 32, c0 = blockIdx.y * 32;
  int lr = threadIdx.x >> 5, lc = threadIdx.x & 31;
#pragma unroll
  for (int i = 0; i < 4; ++i) {
    int r = r0 + lr + i * 8, c = c0 + lc;
    float v = 0.f;
    if (r < R && c < C) {
      size_t idx = (size_t)r * C + c;
      for (int z = 0; z < ks; ++z) v += Cp[(size_t)z * mn + idx];
    }
    t[lr + i * 8][lc] = v;
  }
  __syncthreads();
#pragma unroll
  for (int i = 0; i < 4; ++i) {
    int c = c0 + lr + i * 8, r = r0 + lc;
    if (c < C) {
      float v = t[lc][lr + i * 8];
      if (r < R) v *= disv[r];
      __bf16 h = (__bf16)v;
      oh[(size_t)c * Rp + r] = h;
      ol[(size_t)c * Rp + r] = (__bf16)(v - (float)h);
    }
  }
}

static __global__ void ghilo_k(const float* __restrict__ src, const int* __restrict__ perm,
                               const float* __restrict__ sv, __bf16* __restrict__ oh,
                               __bf16* __restrict__ ol, int k) {
  int idx = blockIdx.x * blockDim.x + threadIdx.x;
  if (idx < k * HIDF) {
    int r = idx >> 8;
    float v = src[(size_t)perm[r] * HIDF + (idx & 255)] * sv[r];
    __bf16 h = (__bf16)v;
    oh[idx] = h;
    ol[idx] = (__bf16)(v - (float)h);
  }
}

// ---------------- MFMA GEMM: split-K, global_load_lds, dbuf, optional row-gather ----------------
template <int BM, int BN>
static __global__ __launch_bounds__(256) void mgemm_k(
    const __bf16* __restrict__ A0, const __bf16* __restrict__ A1g, const __bf16* __restrict__ A2g,
    const __bf16* __restrict__ B0, const __bf16* __restrict__ B1g, const __bf16* __restrict__ B2g,
    const int* __restrict__ pA, const int* __restrict__ pB,
    int nseg, float* __restrict__ Cp, int M, int N, int Kp, int kchunk) {
  constexpr int FM = BM / 32, FN = BN / 32;
  __shared__ __bf16 As[2][BM * 64];
  __shared__ __bf16 Bs[2][BN * 64];
  int tid = threadIdx.x;
  int lane = tid & 63, wave = tid >> 6;
  int wx = wave & 1, wy = wave >> 1;
  int l15 = lane & 15, l4 = lane >> 4;
  int brow = blockIdx.y * BM, bcol = blockIdx.x * BN;
  int wrow = wy * (BM / 2), wcol = wx * (BN / 2);
  int srow = lane >> 3, slot = lane & 7;
  int k_beg = blockIdx.z * kchunk;
  int ksteps = kchunk >> 6;
  int nsteps = nseg * ksteps;
  const __bf16* segA[3] = {A0, A1g, A2g};
  const __bf16* segB[3] = {B0, B1g, B2g};

  int rowA[BM / 32], rowB[BN / 32];
#pragma unroll
  for (int i = 0; i < BM / 32; ++i) {
    int rl = (i * 4 + wave) * 8 + srow;
    int gr = brow + rl;
    if (gr >= M) gr = M - 1;
    rowA[i] = pA ? pA[gr] : gr;
  }
#pragma unroll
  for (int i = 0; i < BN / 32; ++i) {
    int rl = (i * 4 + wave) * 8 + srow;
    int gc = bcol + rl;
    if (gc >= N) gc = N - 1;
    rowB[i] = pB ? pB[gc] : gc;
  }

  auto stage = [&](int buf, int t) {
    int seg = t / ksteps;
    int k0 = k_beg + ((t - seg * ksteps) << 6);
    const __bf16* Ag = segA[seg];
    const __bf16* Bg = segB[seg];
#pragma unroll
    for (int i = 0; i < BM / 32; ++i) {
      int rl = (i * 4 + wave) * 8 + srow;
      int col = k0 + ((slot ^ (rl & 7)) << 3);
      GLDS16(Ag + (size_t)rowA[i] * Kp + col, &As[buf][(i * 4 + wave) * 8 * 64]);
    }
#pragma unroll
    for (int i = 0; i < BN / 32; ++i) {
      int rl = (i * 4 + wave) * 8 + srow;
      int col = k0 + ((slot ^ (rl & 7)) << 3);
      GLDS16(Bg + (size_t)rowB[i] * Kp + col, &Bs[buf][(i * 4 + wave) * 8 * 64]);
    }
  };

  f32x4 acc[FM][FN] = {};
  stage(0, 0);
  __syncthreads();
  int cur = 0;
  for (int t = 0; t < nsteps; ++t) {
    if (t + 1 < nsteps) stage(cur ^ 1, t + 1);
#pragma unroll
    for (int sub = 0; sub < 2; ++sub) {
      bf16x8 af[FM], bfv[FN];
#pragma unroll
      for (int i = 0; i < FM; ++i) {
        int r = wrow + i * 16 + l15;
        af[i] = *(const bf16x8*)(&As[cur][r * 64 + (((sub * 4 + l4) ^ (r & 7)) << 3)]);
      }
#pragma unroll
      for (int j = 0; j < FN; ++j) {
        int r = wcol + j * 16 + l15;
        bfv[j] = *(const bf16x8*)(&Bs[cur][r * 64 + (((sub * 4 + l4) ^ (r & 7)) << 3)]);
      }
#pragma unroll
      for (int i = 0; i < FM; ++i)
#pragma unroll
        for (int j = 0; j < FN; ++j)
          acc[i][j] = __builtin_amdgcn_mfma_f32_16x16x32_bf16(af[i], bfv[j], acc[i][j], 0, 0, 0);
    }
    __syncthreads();
    cur ^= 1;
  }
  size_t zoff = (size_t)blockIdx.z * M * N;
#pragma unroll
  for (int i = 0; i < FM; ++i)
#pragma unroll
    for (int j = 0; j < FN; ++j) {
      int col = bcol + wcol + j * 16 + l15;
      if (col < N) {
#pragma unroll
        for (int q = 0; q < 4; ++q) {
          int row = brow + wrow + i * 16 + l4 * 4 + q;
          if (row < M) Cp[zoff + (size_t)row * N + col] = acc[i][j][q];
        }
      }
    }
}

// ---------------- epilogues (Ahat = A+2I in operand -> no xw term) ----------------
static __global__ __launch_bounds__(256) void epi_score_k(
    const float* __restrict__ zp, int ks, int mn,
    const float* __restrict__ disv, const float* __restrict__ bias,
    const float* __restrict__ p, float* __restrict__ outx, float* __restrict__ sc) {
  int r = blockIdx.x, tid = threadIdx.x;
  size_t idx = (size_t)r * HIDF + tid;
  float zv = 0.f;
  for (int z = 0; z < ks; ++z) zv += zp[(size_t)z * mn + idx];
  float v = fmaxf(disv[r] * zv + bias[tid], 0.0f);
  outx[idx] = v;
  float wv = p[tid];
  float s = v * wv, q = wv * wv;
  __shared__ float sh[4], sh2[4];
  int lane = tid & 63, wid = tid >> 6;
#pragma unroll
  for (int o = 32; o > 0; o >>= 1) { s += __shfl_down(s, o, 64); q += __shfl_down(q, o, 64); }
  if (lane == 0) { sh[wid] = s; sh2[wid] = q; }
  __syncthreads();
  if (tid == 0)
    sc[r] = tanhf((sh[0] + sh[1] + sh[2] + sh[3]) / sqrtf(sh2[0] + sh2[1] + sh2[2] + sh2[3]));
}

static __global__ void unpool_epi_k(const float* __restrict__ base, const float* __restrict__ zp,
                                    int ks, int mn,
                                    const float* __restrict__ disv, const float* __restrict__ bias,
                                    const int* __restrict__ pos, __bf16* __restrict__ oh,
                                    __bf16* __restrict__ ol, int n) {
  int idx = blockIdx.x * blockDim.x + threadIdx.x;
  if (idx < n * HIDF) {
    int i = idx >> 8, j = idx & 255;
    int p = pos[i];
    float v = base[idx];
    if (p >= 0) {
      size_t pidx = (size_t)p * HIDF + j;
      float zv = 0.f;
      for (int z = 0; z < ks; ++z) zv += zp[(size_t)z * mn + pidx];
      v += fmaxf(disv[p] * zv + bias[j], 0.0f);
    }
    __bf16 h = (__bf16)v;
    oh[idx] = h;
    ol[idx] = (__bf16)(v - (float)h);
  }
}

// GEMM over (X+2I) operands gives X^2+4X+4I; target offdiag X^2+2X = gemm - 2*X = gemm - 2*srow.
// Writes Ahat_next = target + 2I (diag=2 exact); dis = rsqrt(rowsum).
static __global__ __launch_bounds__(256) void aug_epi_k(
    const float* __restrict__ Cp, int ks, int mn, int n, int dstL,
    const __bf16* __restrict__ srcH, const __bf16* __restrict__ srcL, int srcLen,
    const int* __restrict__ permv, __bf16* __restrict__ bh, __bf16* __restrict__ bl,
    float* __restrict__ dis) {
  __shared__ int pm[1000];
  __shared__ float srow[2048];
  __shared__ float sh[4];
  int r = blockIdx.x;
  int tid = threadIdx.x, lane = tid & 63, wave = tid >> 6;
  int vi = permv[r];
  for (int c = tid; c < n; c += 256) pm[c] = permv[c];
  for (int k = tid; k < srcLen; k += 256) {
    float v = (float)srcH[(size_t)vi * srcLen + k];
    if (srcL) v += (float)srcL[(size_t)vi * srcLen + k];
    srow[k] = v;
  }
  __syncthreads();
  float ssum = 0.f;
  for (int c = tid; c < dstL; c += 256) {
    float v = 0.f;
    if (c < n) {
      if (c == r) {
        v = 2.0f;  // +2I of next level, exact
      } else {
        for (int z = 0; z < ks; ++z) v += Cp[(size_t)z * mn + (size_t)r * n + c];
        v -= 2.0f * srow[pm[c]];
      }
    }
    __bf16 h = (__bf16)v;
    bh[(size_t)r * dstL + c] = h;
    bl[(size_t)r * dstL + c] = (__bf16)(v - (float)h);
    ssum += v;
  }
#pragma unroll
  for (int o = 32; o > 0; o >>= 1) ssum += __shfl_down(ssum, o, 64);
  if (lane == 0) sh[wave] = ssum;
  __syncthreads();
  if (tid == 0) dis[r] = rsqrtf(sh[0] + sh[1] + sh[2] + sh[3]);
}

// ---------------- pooling ----------------
static __global__ __launch_bounds__(256) void topk_rank_k(const float* __restrict__ sc, int n, int k,
                                                          int* __restrict__ perm, float* __restrict__ sv,
                                                          int* __restrict__ pos) {
  __shared__ float s[N0 + 8];
  int tid = threadIdx.x, lane = tid & 63, wave = tid >> 6;
  for (int i = tid; i < n; i += 256) s[i] = sc[i];
  __syncthreads();
  int i = blockIdx.x * 4 + wave;
  if (i < n) {
    float si = s[i];
    int rank = 0;
    for (int j = lane; j < n; j += 64) {
      float sj = s[j];
      rank += (sj > si) || (sj == si && j < i);
    }
#pragma unroll
    for (int o = 32; o > 0; o >>= 1) rank += __shfl_down(rank, o, 64);
    if (lane == 0) {
      pos[i] = (rank < k) ? rank : -1;
      if (rank < k) { perm[rank] = i; sv[rank] = si; }
    }
  }
}

// fused final epilogue + log_softmax
static __global__ void epilsm_k(const float* __restrict__ zb, const float* __restrict__ dis,
                                const float* __restrict__ b, float* __restrict__ out) {
  int r = blockIdx.x, j = threadIdx.x;
  float v = dis[r] * zb[r * OUTC + j] + b[j];
  float m = v;
#pragma unroll
  for (int o = 32; o > 0; o >>= 1) m = fmaxf(m, __shfl_xor(m, o, 64));
  float e = expf(v - m), s = e;
#pragma unroll
  for (int o = 32; o > 0; o >>= 1) s += __shfl_xor(s, o, 64);
  out[r * OUTC + j] = v - m - logf(s);
}

// ---------------- host ----------------
extern "C" void kernel_launch(void* const* d_in, const int* in_sizes, int n_in,
                              void* d_out, int out_size, void* d_ws, size_t ws_size,
                              hipStream_t stream) {
  const float* x  = (const float*)d_in[0];
  const int* ei   = (const int*)d_in[1];
  const float* W0 = (const float*)d_in[2];
  const float* b0 = (const float*)d_in[3];
  const float* W1 = (const float*)d_in[4];
  const float* b1 = (const float*)d_in[5];
  const float* W2 = (const float*)d_in[6];
  const float* b2 = (const float*)d_in[7];
  const float* W3 = (const float*)d_in[8];
  const float* b3 = (const float*)d_in[9];
  const float* p1 = (const float*)d_in[10];
  const float* p2 = (const float*)d_in[11];
  const float* p3 = (const float*)d_in[12];
  const float* U0 = (const float*)d_in[13];
  const float* c0 = (const float*)d_in[14];
  const float* U1 = (const float*)d_in[15];
  const float* c1 = (const float*)d_in[16];
  const float* U2 = (const float*)d_in[17];
  const float* c2 = (const float*)d_in[18];
  (void)in_sizes; (void)n_in; (void)out_size; (void)ws_size;

  char* basep = (char*)d_ws;
  size_t off = 0;
  auto alloc = [&](size_t bytes) {
    void* p = basep + off;
    off += (bytes + 255) & ~(size_t)255;
    return p;
  };

  // fp32
  float* xw  = (float*)alloc((size_t)N0 * HIDF * 4);
  float* zb  = (float*)alloc((size_t)N0 * HIDF * 4);
  float* x0  = (float*)alloc((size_t)N0 * HIDF * 4);
  float* x1  = (float*)alloc((size_t)KP1 * HIDF * 4);
  float* x2  = (float*)alloc((size_t)KP2 * HIDF * 4);
  float* Cpart = (float*)alloc((size_t)20 * 1024 * 1024);
  // bf16
  __bf16* bfAh = (__bf16*)alloc((size_t)N0 * INC * 2);
  __bf16* bfAl = (__bf16*)alloc((size_t)N0 * INC * 2);
  __bf16* bfBh = (__bf16*)alloc((size_t)HIDF * KP1P * 2);
  __bf16* bfBl = (__bf16*)alloc((size_t)HIDF * KP1P * 2);
  __bf16* A1bf  = (__bf16*)alloc((size_t)KP1 * KP1P * 2);
  __bf16* A1tbf = (__bf16*)alloc((size_t)KP1 * KP1P * 2);
  __bf16* A2bh  = (__bf16*)alloc((size_t)KP2 * KP2P * 2);
  __bf16* A2bl  = (__bf16*)alloc((size_t)KP2 * KP2P * 2);
  __bf16* A2tbh = (__bf16*)alloc((size_t)KP2 * KP2P * 2);
  __bf16* A2tbl = (__bf16*)alloc((size_t)KP2 * KP2P * 2);
  __bf16* A3bh  = (__bf16*)alloc((size_t)KP3 * KP3P * 2);
  __bf16* A3bl  = (__bf16*)alloc((size_t)KP3 * KP3P * 2);
  // weight operands
  __bf16* w0h = (__bf16*)alloc((size_t)HIDF * 512 * 2);
  __bf16* w0l = (__bf16*)alloc((size_t)HIDF * 512 * 2);
  __bf16* w1h = (__bf16*)alloc((size_t)HIDF * 256 * 2);
  __bf16* w1l = (__bf16*)alloc((size_t)HIDF * 256 * 2);
  __bf16* w2h = (__bf16*)alloc((size_t)HIDF * 256 * 2);
  __bf16* w2l = (__bf16*)alloc((size_t)HIDF * 256 * 2);
  __bf16* w3h = (__bf16*)alloc((size_t)HIDF * 256 * 2);
  __bf16* w3l = (__bf16*)alloc((size_t)HIDF * 256 * 2);
  __bf16* u0h = (__bf16*)alloc((size_t)HIDF * 256 * 2);
  __bf16* u0l = (__bf16*)alloc((size_t)HIDF * 256 * 2);
  __bf16* u1h = (__bf16*)alloc((size_t)HIDF * 256 * 2);
  __bf16* u1l = (__bf16*)alloc((size_t)HIDF * 256 * 2);
  __bf16* u2h = (__bf16*)alloc((size_t)OUTC * 256 * 2);
  __bf16* u2l = (__bf16*)alloc((size_t)OUTC * 256 * 2);
  // small
  float* sc   = (float*)alloc(N0 * 4);
  float* sv   = (float*)alloc(KP1 * 4);
  int* perm1  = (int*)alloc(KP1 * 4);
  int* perm2  = (int*)alloc(KP2 * 4);
  int* perm3  = (int*)alloc(KP3 * 4);
  int* pos1   = (int*)alloc(N0 * 4);
  int* pos2   = (int*)alloc(KP1 * 4);
  int* pos3   = (int*)alloc(KP2 * 4);
  float* dis0 = (float*)alloc(N0 * 4);
  float* dis1 = (float*)alloc(KP1 * 4);
  float* dis2 = (float*)alloc(KP2 * 4);
  float* dis3 = (float*)alloc(KP3 * 4);
  int* cf     = (int*)alloc((size_t)2 * 3072 * 4);
  int* cnt_d  = cf;
  int* fl_d   = cf + 3072;
  int* st_d   = (int*)alloc((N0 + 4) * 4);
  int* bk_d   = (int*)alloc(NE * 4);

  auto mg = [&](int bm, int bn, const __bf16* a0, const __bf16* a1, const __bf16* a2,
                const __bf16* bb0, const __bf16* bb1, const __bf16* bb2,
                const int* pA, const int* pB, int nseg, float* Cdst,
                int M, int N, int Kp, int ks, int kchunk) {
    dim3 g((N + bn - 1) / bn, (M + bm - 1) / bm, ks);
    if (bm == 128 && bn == 128)
      mgemm_k<128, 128><<<g, 256, 0, stream>>>(a0, a1, a2, bb0, bb1, bb2, pA, pB, nseg, Cdst, M, N, Kp, kchunk);
    else if (bm == 128)
      mgemm_k<128, 64><<<g, 256, 0, stream>>>(a0, a1, a2, bb0, bb1, bb2, pA, pB, nseg, Cdst, M, N, Kp, kchunk);
    else if (bn == 128)
      mgemm_k<64, 128><<<g, 256, 0, stream>>>(a0, a1, a2, bb0, bb1, bb2, pA, pB, nseg, Cdst, M, N, Kp, kchunk);
    else
      mgemm_k<64, 64><<<g, 256, 0, stream>>>(a0, a1, a2, bb0, bb1, bb2, pA, pB, nseg, Cdst, M, N, Kp, kchunk);
  };

  // weight GEMM: ks=1, direct write to xw
  auto wgemm = [&](const __bf16* wh, const __bf16* wl, int fin, int fout, int n) {
    int Kp = (fin + 63) & ~63;
    mg(64, 64, bfAh, bfAh, bfAl, wh, wl, wh, nullptr, nullptr, 3, xw, n, fout, Kp, 1, Kp);
  };

  // prop GEMM: B-operand from xw, GEMM into Cpart with split-K
  auto propg = [&](const __bf16* Abh, const __bf16* Abl, int asegs, int n, int Kp, int bm, int bn,
                   int ks, int kchunk, const float* disv) {
    dim3 tg(Kp / 32, HIDF / 32);
    redtconv_k<<<tg, 256, 0, stream>>>(xw, 1, 0, n, HIDF, Kp, bfBh, bfBl, disv);
    if (asegs == 1) mg(bm, bn, Abh, Abh, nullptr, bfBh, bfBl, nullptr, nullptr, nullptr, 2, Cpart, n, HIDF, Kp, ks, kchunk);
    else            mg(bm, bn, Abh, Abh, Abl, bfBh, bfBl, bfBh, nullptr, nullptr, 3, Cpart, n, HIDF, Kp, ks, kchunk);
  };

  // ---- CSR build + weight conversions ----
  hipMemsetAsync(cf, 0, (size_t)2 * 3072 * 4, stream);
  count_k<<<(NE + 255) / 256, 256, 0, stream>>>(ei, cnt_d);
  {
    TDescs ds;
    ds.d[0] = {W0, w0h, w0l, INC, HIDF, 512};
    ds.d[1] = {W1, w1h, w1l, HIDF, HIDF, 256};
    ds.d[2] = {W2, w2h, w2l, HIDF, HIDF, 256};
    ds.d[3] = {W3, w3h, w3l, HIDF, HIDF, 256};
    ds.d[4] = {U0, u0h, u0l, HIDF, HIDF, 256};
    ds.d[5] = {U1, u1h, u1l, HIDF, HIDF, 256};
    ds.d[6] = {U2, u2h, u2l, HIDF, OUTC, 256};
    wtconv_k<<<dim3(16, 8, 7), 256, 0, stream>>>(ds);
  }
  scan_excl_k<<<1, 1024, 0, stream>>>(cnt_d, st_d, N0, dis0);
  scatter_k<<<(NE + 255) / 256, 256, 0, stream>>>(ei, st_d, fl_d, bk_d);

  // ---- down conv 0 (sparse propagation), epi fused with score(p1) ----
  conv_hilo_k<<<((size_t)N0 * INC + 255) / 256, 256, 0, stream>>>(x, N0, INC, INC, bfAh, bfAl);
  wgemm(w0h, w0l, INC, HIDF, N0);
  spmm_sc_k<<<N0, HIDF, 0, stream>>>(st_d, bk_d, xw, dis0, zb, HIDF);
  epi_score_k<<<N0, 256, 0, stream>>>(zb, 1, 0, dis0, b0, p1, x0, sc);
  topk_rank_k<<<(N0 + 3) / 4, 256, 0, stream>>>(sc, N0, KP1, perm1, sv, pos1);

  // ---- masked augment(A) -> Ahat1 = aug + 2I ----
  augA_masked_k<<<KP1, 256, 0, stream>>>(st_d, bk_d, perm1, pos1, A1bf, dis1);

  // ---- conv 1, epi fused with score(p2) ----
  ghilo_k<<<((size_t)KP1 * HIDF + 255) / 256, 256, 0, stream>>>(x0, perm1, sv, bfAh, bfAl, KP1);
  wgemm(w1h, w1l, HIDF, HIDF, KP1);
  propg(A1bf, nullptr, 1, KP1, KP1P, 128, 128, 8, 256, dis1);
  epi_score_k<<<KP1, 256, 0, stream>>>(Cpart, 8, KP1 * HIDF, dis1, b1, p2, x1, sc);
  topk_rank_k<<<(KP1 + 3) / 4, 256, 0, stream>>>(sc, KP1, KP2, perm2, sv, pos2);

  // ---- augment(A1): gathered GEMM over Ahat1 + epi (-2A fix) ----
  btrans_k<<<dim3(KP1P / 32, (KP1 + 31) / 32), 256, 0, stream>>>(A1bf, nullptr, A1tbf, nullptr,
                                                                 KP1, KP1P, KP1, KP1P);
  mg(128, 128, A1bf, nullptr, nullptr, A1tbf, nullptr, nullptr, perm2, perm2,
     1, Cpart, KP2, KP2, KP1P, 4, 512);
  aug_epi_k<<<KP2, 256, 0, stream>>>(Cpart, 4, KP2 * KP2, KP2, KP2P, A1bf, nullptr, KP1P, perm2,
                                     A2bh, A2bl, dis2);

  // ---- conv 2, epi fused with score(p3) ----
  ghilo_k<<<((size_t)KP2 * HIDF + 255) / 256, 256, 0, stream>>>(x1, perm2, sv, bfAh, bfAl, KP2);
  wgemm(w2h, w2l, HIDF, HIDF, KP2);
  propg(A2bh, A2bl, 2, KP2, KP2P, 64, 128, 8, 128, dis2);
  epi_score_k<<<KP2, 256, 0, stream>>>(Cpart, 8, KP2 * HIDF, dis2, b2, p3, x2, sc);
  topk_rank_k<<<(KP2 + 3) / 4, 256, 0, stream>>>(sc, KP2, KP3, perm3, sv, pos3);

  // ---- augment(A2): gathered GEMM hi/lo over Ahat2 + epi ----
  btrans_k<<<dim3(KP2P / 32, (KP2 + 31) / 32), 256, 0, stream>>>(A2bh, A2bl, A2tbh, A2tbl,
                                                                 KP2, KP2P, KP2, KP2P);
  mg(64, 64, A2bh, A2bh, A2bl, A2tbh, A2tbl, A2tbh, perm3, perm3, 3, Cpart, KP3, KP3, KP2P, 4, 256);
  aug_epi_k<<<KP3, 256, 0, stream>>>(Cpart, 4, KP3 * KP3, KP3, KP3P, A2bh, A2bl, KP2P, perm3,
                                     A3bh, A3bl, dis3);

  // ---- conv 3 (epi fused into first unpool) ----
  ghilo_k<<<((size_t)KP3 * HIDF + 255) / 256, 256, 0, stream>>>(x2, perm3, sv, bfAh, bfAl, KP3);
  wgemm(w3h, w3l, HIDF, HIDF, KP3);
  propg(A3bh, A3bl, 2, KP3, KP3P, 64, 128, 8, 64, dis3);
  unpool_epi_k<<<(KP2 * HIDF + 255) / 256, 256, 0, stream>>>(x2, Cpart, 8, KP3 * HIDF, dis3, b3,
                                                             pos3, bfAh, bfAl, KP2);

  // ---- up conv on A2 (epi fused into next unpool) ----
  wgemm(u0h, u0l, HIDF, HIDF, KP2);
  propg(A2bh, A2bl, 2, KP2, KP2P, 64, 128, 8, 128, dis2);
  unpool_epi_k<<<(KP1 * HIDF + 255) / 256, 256, 0, stream>>>(x1, Cpart, 8, KP2 * HIDF, dis2, c0,
                                                             pos2, bfAh, bfAl, KP1);

  // ---- up conv on A1 (epi fused into next unpool) ----
  wgemm(u1h, u1l, HIDF, HIDF, KP1);
  propg(A1bf, nullptr, 1, KP1, KP1P, 128, 128, 8, 256, dis1);
  unpool_epi_k<<<(N0 * HIDF + 255) / 256, 256, 0, stream>>>(x0, Cpart, 8, KP1 * HIDF, dis1, c1,
                                                            pos1, bfAh, bfAl, N0);

  // ---- final conv on A (sparse) + log_softmax ----
  wgemm(u2h, u2l, HIDF, OUTC, N0);
  spmm_sc_k<<<N0, OUTC, 0, stream>>>(st_d, bk_d, xw, dis0, zb, OUTC);
  epilsm_k<<<N0, OUTC, 0, stream>>>(zb, dis0, c2, (float*)d_out);
}